// Round 8
// baseline (892.214 us; speedup 1.0000x reference)
//
#include <hip/hip_runtime.h>
#include <cstdint>
#include <cstddef>

// ---------------------------------------------------------------------------
// Submanifold sparse conv net, MFMA bf16 implicit-GEMM.
// Round 8: round-5 guarded burst body + RT=4 (256 rows/block) to halve B
// re-fetch from L2 (the measured bottleneck), CT split via grid.y to bound
// accumulator VGPRs. Transposed pairs [row][32] int4. Deep levels unchanged.
// ---------------------------------------------------------------------------

typedef __attribute__((ext_vector_type(8))) short short8v;
typedef __attribute__((ext_vector_type(4))) float f32x4;

static inline int cdiv_h(int a, int b) { return (a + b - 1) / b; }

__device__ inline unsigned short f2bf(float f) {
    unsigned int u = __builtin_bit_cast(unsigned int, f);
    u += 0x7FFFu + ((u >> 16) & 1u);
    return (unsigned short)(u >> 16);
}
__device__ inline float bf2f(unsigned short h) {
    unsigned int u = ((unsigned int)h) << 16;
    return __builtin_bit_cast(float, u);
}

__global__ void set_count_k(int* counts, int n) { counts[0] = n; }

__global__ void scatter_grid_k(const int* __restrict__ coords, const int* __restrict__ cnt,
                               int* __restrict__ grid, int S)
{
    int i = blockIdx.x * blockDim.x + threadIdx.x;
    if (i >= cnt[0]) return;
    int z = coords[i * 4 + 1], y = coords[i * 4 + 2], x = coords[i * 4 + 3];
    grid[(z * S + y) * S + x] = i;
}

// pairs_t[row][32]: taps 0..26, pad 27..31 = -1. int4-aligned per row.
__global__ void build_pairs_k(const int* __restrict__ coords, const int* __restrict__ cnt,
                              const int* __restrict__ grid, int* __restrict__ pairs_t, int S)
{
    int i = blockIdx.x * blockDim.x + threadIdx.x;
    if (i >= cnt[0]) return;
    int z = coords[i * 4 + 1], y = coords[i * 4 + 2], x = coords[i * 4 + 3];
    int4* dst = reinterpret_cast<int4*>(pairs_t + (size_t)i * 32);
#pragma unroll
    for (int g = 0; g < 7; ++g) {
        int4 q;
#pragma unroll
        for (int j = 0; j < 4; ++j) {
            int k = g * 4 + j;
            int v = -1;
            if (k < 27) {
                int nz = z + k / 9 - 1;
                int ny = y + (k / 3) % 3 - 1;
                int nx = x + k % 3 - 1;
                if (nz >= 0 && nz < S && ny >= 0 && ny < S && nx >= 0 && nx < S)
                    v = grid[(nz * S + ny) * S + nx];
            }
            ((int*)&q)[j] = v;
        }
        dst[g] = q;
    }
}

// ---- fused weight pre-pack: fp32 [27][CIN][COUT] -> bf16 fragment tiles -----
struct PackArgs {
    const float* src[13];
    unsigned short* dst[13];
    int cin[13];
    int cout[13];
    int tileStart[14];
};

__global__ __launch_bounds__(256) void pack_all_k(PackArgs pa)
{
    int g = blockIdx.x * 4 + ((int)threadIdx.x >> 6);
    int lane = (int)threadIdx.x & 63;
    if (g >= pa.tileStart[13]) return;
    int li = 0;
    while (li < 12 && g >= pa.tileStart[li + 1]) ++li;
    int tile = g - pa.tileStart[li];
    int CIN = pa.cin[li], COUT = pa.cout[li];
    int NS = CIN >> 5, NT = COUT >> 4;
    int t = tile % NT;
    int s = (tile / NT) % NS;
    int k = tile / (NT * NS);
    int kabs = s * 32 + (lane >> 4) * 8;
    int c = t * 16 + (lane & 15);
    const float* src = pa.src[li] + ((size_t)(k * CIN + kabs)) * COUT + c;
    unsigned short* dst = pa.dst[li] + (size_t)tile * 512 + lane * 8;
#pragma unroll
    for (int j = 0; j < 8; ++j) dst[j] = f2bf(src[(size_t)j * COUT]);
}

// ---- first layer (CIN=3) fp32 vector, writes bf16 ---------------------------
__global__ __launch_bounds__(256) void conv0_k(
    const float* __restrict__ fin, const float* __restrict__ W,
    const int* __restrict__ pairs_t, const int* __restrict__ cnt,
    unsigned short* __restrict__ fout)
{
    const int row = blockIdx.x * 16 + ((int)threadIdx.x >> 4);
    const int cg = ((int)threadIdx.x & 15) * 4;
    if (row >= cnt[0]) return;
    float a0 = 0, a1 = 0, a2 = 0, a3 = 0;
    for (int k = 0; k < 27; ++k) {
        int nb = pairs_t[(size_t)row * 32 + k];
        if (nb < 0) continue;
        const float* fr = fin + (size_t)nb * 3;
        const float* wk = W + (size_t)k * 3 * 64 + cg;
#pragma unroll
        for (int ci = 0; ci < 3; ++ci) {
            float f = fr[ci];
            float4 w = *reinterpret_cast<const float4*>(wk + ci * 64);
            a0 += f * w.x; a1 += f * w.y; a2 += f * w.z; a3 += f * w.w;
        }
    }
    size_t o = (size_t)row * 64 + cg;
    fout[o] = f2bf(a0); fout[o + 1] = f2bf(a1);
    fout[o + 2] = f2bf(a2); fout[o + 3] = f2bf(a3);
}

// ---- MFMA conv (levels 0-2): round-5 guarded burst body, RT row-tiles -------
template <int CIN, int COUT, int RT, int CT, bool OUTF32>
__global__ __launch_bounds__(256) void conv_mfma_k(
    const unsigned short* __restrict__ fin, const unsigned short* __restrict__ Wp,
    const int* __restrict__ pairs_t, const int* __restrict__ cnt,
    void* __restrict__ fout)
{
    constexpr int NS = CIN / 32, NT = COUT / 16;
    const int lane = (int)threadIdx.x & 63;
    const int wave = (int)threadIdx.x >> 6;
    const int l15 = lane & 15, lhi = lane >> 4;
    const int M = cnt[0];
    const int rowBase = (blockIdx.x * 4 + wave) * (RT * 16);
    if (rowBase >= M) return;
    const int ct0 = blockIdx.y * CT;

    const unsigned short* __restrict__ finL = fin + (size_t)lhi * 8;
    const unsigned short* __restrict__ WpL  = Wp + (size_t)lane * 8 + (size_t)ct0 * 512;

    f32x4 acc[RT][CT];
#pragma unroll
    for (int a = 0; a < RT; ++a)
#pragma unroll
        for (int b = 0; b < CT; ++b) acc[a][b] = (f32x4){0.f, 0.f, 0.f, 0.f};

    int  rowC[RT];
    bool rOK[RT];
#pragma unroll
    for (int rt = 0; rt < RT; ++rt) {
        int r = rowBase + rt * 16 + l15;
        rOK[rt]  = r < M;
        rowC[rt] = rOK[rt] ? r : (M - 1);
    }

#pragma unroll
    for (int kg = 0; kg < 7; ++kg) {
        int4 nb4[RT];
#pragma unroll
        for (int rt = 0; rt < RT; ++rt) {
            nb4[rt] = *reinterpret_cast<const int4*>(pairs_t + (size_t)rowC[rt] * 32 + kg * 4);
            if (!rOK[rt]) nb4[rt] = make_int4(-1, -1, -1, -1);
        }
#pragma unroll
        for (int j = 0; j < 4; ++j) {
            const int k = kg * 4 + j;
            if (k >= 27) continue;  // constant-folds
            int nb[RT];
#pragma unroll
            for (int rt = 0; rt < RT; ++rt)
                nb[rt] = (j == 0) ? nb4[rt].x : (j == 1) ? nb4[rt].y
                       : (j == 2) ? nb4[rt].z : nb4[rt].w;

            int act[RT];
            bool anyAct = false;
#pragma unroll
            for (int rt = 0; rt < RT; ++rt) {
                act[rt] = __any(nb[rt] >= 0);
                anyAct = anyAct || (act[rt] != 0);
            }
            if (!anyAct) continue;

            const unsigned short* wk = WpL + (size_t)k * (NS * NT * 512);
            short8v bfr[NS][CT];
#pragma unroll
            for (int s = 0; s < NS; ++s)
#pragma unroll
                for (int t = 0; t < CT; ++t)
                    bfr[s][t] = *reinterpret_cast<const short8v*>(
                        wk + ((size_t)s * NT + t) * 512);

            short8v afr[NS][RT];
#pragma unroll
            for (int s = 0; s < NS; ++s)
#pragma unroll
                for (int rt = 0; rt < RT; ++rt) {
                    afr[s][rt] = (short8v){};
                    if (nb[rt] >= 0)
                        afr[s][rt] = *reinterpret_cast<const short8v*>(
                            finL + (size_t)nb[rt] * CIN + s * 32);
                }

#pragma unroll
            for (int s = 0; s < NS; ++s)
#pragma unroll
                for (int rt = 0; rt < RT; ++rt) {
                    if (!act[rt]) continue;
#pragma unroll
                    for (int t = 0; t < CT; ++t)
                        acc[rt][t] = __builtin_amdgcn_mfma_f32_16x16x32_bf16(
                            afr[s][rt], bfr[s][t], acc[rt][t], 0, 0, 0);
                }
        }
    }

    // epilogue: C layout col = lane&15, row = (lane>>4)*4 + reg
#pragma unroll
    for (int rt = 0; rt < RT; ++rt) {
#pragma unroll
        for (int j = 0; j < 4; ++j) {
            int r = rowBase + rt * 16 + lhi * 4 + j;
            if (r >= M) continue;
#pragma unroll
            for (int t = 0; t < CT; ++t) {
                int c = (ct0 + t) * 16 + l15;
                if constexpr (OUTF32)
                    ((float*)fout)[(size_t)r * COUT + c] = acc[rt][t][j];
                else
                    ((unsigned short*)fout)[(size_t)r * COUT + c] = f2bf(acc[rt][t][j]);
            }
        }
    }
}

// ---- deep-level conv (levels 3-6): 1-wave blocks, tap/cout split, fp32 atomics
template <int CIN, int COUT, int CTD, int TG>
__global__ __launch_bounds__(64) void conv_deep_k(
    const unsigned short* __restrict__ fin, const unsigned short* __restrict__ Wp,
    const int* __restrict__ pairs_t, const int* __restrict__ cnt,
    float* __restrict__ fout)
{
    constexpr int NS = CIN / 32, NT = COUT / 16;
    const int lane = (int)threadIdx.x;
    const int l15 = lane & 15, lhi = lane >> 4;
    const int M = cnt[0];
    if ((int)blockIdx.x * 16 >= M) return;
    const int row = blockIdx.x * 16 + l15;
    const int ct0 = blockIdx.y * CTD;
    const int k0 = blockIdx.z * TG;

    f32x4 acc[CTD];
#pragma unroll
    for (int t = 0; t < CTD; ++t) acc[t] = (f32x4){0.f, 0.f, 0.f, 0.f};

    bool anyTap = false;
#pragma unroll
    for (int kk = 0; kk < TG; ++kk) {
        const int k = k0 + kk;
        int nb = (row < M) ? pairs_t[(size_t)row * 32 + k] : -1;
        if (!__any(nb >= 0)) continue;
        anyTap = true;
        const unsigned short* wk = Wp + (size_t)k * NS * NT * 512 + (size_t)lane * 8;
#pragma unroll
        for (int s = 0; s < NS; ++s) {
            short8v a = (short8v){};
            if (nb >= 0)
                a = *reinterpret_cast<const short8v*>(
                    fin + (size_t)nb * CIN + s * 32 + lhi * 8);
#pragma unroll
            for (int t = 0; t < CTD; ++t) {
                short8v b = *reinterpret_cast<const short8v*>(
                    wk + ((size_t)s * NT + ct0 + t) * 512);
                acc[t] = __builtin_amdgcn_mfma_f32_16x16x32_bf16(a, b, acc[t], 0, 0, 0);
            }
        }
    }
    if (!anyTap) return;

#pragma unroll
    for (int t = 0; t < CTD; ++t)
#pragma unroll
        for (int j = 0; j < 4; ++j) {
            int r = blockIdx.x * 16 + lhi * 4 + j;
            if (r < M)
                atomicAdd(&fout[(size_t)r * COUT + (ct0 + t) * 16 + l15], acc[t][j]);
        }
}

__global__ __launch_bounds__(256) void f32_to_bf16_k(
    const float* __restrict__ src, const int* __restrict__ cnt,
    unsigned short* __restrict__ dst, int C)
{
    int idx = blockIdx.x * 256 + (int)threadIdx.x;
    if (idx / C >= cnt[0]) return;
    dst[idx] = f2bf(src[idx]);
}

// ---- pooling structure: multi-block scan ------------------------------------
__global__ void mark_occ_k(const int* __restrict__ coords, const int* __restrict__ cnt,
                           int* __restrict__ occ, int Sh)
{
    int i = blockIdx.x * blockDim.x + threadIdx.x;
    if (i >= cnt[0]) return;
    int z = coords[i * 4 + 1] >> 1, y = coords[i * 4 + 2] >> 1, x = coords[i * 4 + 3] >> 1;
    occ[(z * Sh + y) * Sh + x] = 1;
}

__global__ __launch_bounds__(256) void scan_sum_k(const int* __restrict__ occ, int P,
                                                  int* __restrict__ bsum)
{
    int base = blockIdx.x * 4096 + (int)threadIdx.x * 16;
    int s = 0;
#pragma unroll
    for (int j = 0; j < 16; ++j) { int i = base + j; s += (i < P) ? occ[i] : 0; }
    for (int off = 1; off < 64; off <<= 1) s += __shfl_xor(s, off);
    __shared__ int ws[4];
    if ((threadIdx.x & 63) == 0) ws[threadIdx.x >> 6] = s;
    __syncthreads();
    if (threadIdx.x == 0) bsum[blockIdx.x] = ws[0] + ws[1] + ws[2] + ws[3];
}

__global__ void scan_offsets_k(const int* __restrict__ bsum, int nb,
                               int* __restrict__ boff, int* __restrict__ cntOut)
{
    int lane = threadIdx.x;  // 64 threads, nb <= 64
    int v = (lane < nb) ? bsum[lane] : 0;
    int incl = v;
    for (int off = 1; off < 64; off <<= 1) {
        int t = __shfl_up(incl, off);
        if (lane >= off) incl += t;
    }
    if (lane < nb) boff[lane] = incl - v;
    if (lane == 63) cntOut[0] = incl;
}

__global__ __launch_bounds__(256) void scan_emit_k(const int* __restrict__ occ, int P,
                                                   const int* __restrict__ boff,
                                                   int* __restrict__ newcoords, int Sh)
{
    __shared__ int ws[4];
    int tid = threadIdx.x;
    int base = blockIdx.x * 4096 + tid * 16;
    int v[16];
    int s = 0;
#pragma unroll
    for (int j = 0; j < 16; ++j) { int i = base + j; v[j] = (i < P) ? occ[i] : 0; s += v[j]; }
    int mysum = s;
    int incl = s;
    for (int off = 1; off < 64; off <<= 1) {
        int t = __shfl_up(incl, off);
        if ((tid & 63) >= off) incl += t;
    }
    if ((tid & 63) == 63) ws[tid >> 6] = incl;
    __syncthreads();
    int waveOff = 0;
    for (int w = 0; w < (tid >> 6); ++w) waveOff += ws[w];
    int r = boff[blockIdx.x] + waveOff + incl - mysum;
    const int SS = Sh * Sh;
#pragma unroll
    for (int j = 0; j < 16; ++j) {
        if (v[j]) {
            int c = base + j;
            newcoords[r * 4 + 0] = 0;
            newcoords[r * 4 + 1] = c / SS;
            newcoords[r * 4 + 2] = (c % SS) / Sh;
            newcoords[r * 4 + 3] = c % Sh;
            ++r;
        }
    }
}

__global__ void pool_max_k(const unsigned short* __restrict__ fin, const int* __restrict__ gridPrev,
                           const int* __restrict__ newcoords, const int* __restrict__ cnt,
                           unsigned short* __restrict__ fout, int C, int Sprev)
{
    int idx = blockIdx.x * blockDim.x + threadIdx.x;
    int r = idx / C, c = idx % C;
    if (r >= cnt[0]) return;
    int z2 = newcoords[r * 4 + 1] * 2;
    int y2 = newcoords[r * 4 + 2] * 2;
    int x2 = newcoords[r * 4 + 3] * 2;
    float best = -3.4e38f;
    unsigned short bb = 0;
#pragma unroll
    for (int d = 0; d < 8; ++d) {
        int z = z2 + (d >> 2), y = y2 + ((d >> 1) & 1), x = x2 + (d & 1);
        int j = gridPrev[(z * Sprev + y) * Sprev + x];
        if (j >= 0) {
            unsigned short u = fin[(size_t)j * C + c];
            float f = bf2f(u);
            if (f > best) { best = f; bb = u; }
        }
    }
    fout[(size_t)r * C + c] = bb;
}

// ---------------------------------------------------------------------------

template <int CIN, int COUT, int RT, int CT, bool OUTF32>
static void launch_cm(const unsigned short* fin, const unsigned short* Wp,
                      const int* pairs_t, const int* cnt, void* fout,
                      int bound, hipStream_t stream)
{
    constexpr int NT = COUT / 16;
    static_assert(CIN % 32 == 0 && COUT % 16 == 0 && NT % CT == 0, "shape");
    dim3 g(cdiv_h(bound, RT * 64), NT / CT);
    conv_mfma_k<CIN, COUT, RT, CT, OUTF32><<<g, 256, 0, stream>>>(
        fin, Wp, pairs_t, cnt, fout);
}

template <int CIN, int COUT, int CTD, int TG>
static void launch_deep(const unsigned short* fin, const unsigned short* Wp,
                        const int* pairs_t, const int* cnt, float* acc,
                        int bound, hipStream_t stream)
{
    constexpr int NT = COUT / 16;
    static_assert(NT % CTD == 0 && 27 % TG == 0, "shape");
    dim3 g(cdiv_h(bound, 16), NT / CTD, 27 / TG);
    conv_deep_k<CIN, COUT, CTD, TG><<<g, 64, 0, stream>>>(fin, Wp, pairs_t, cnt, acc);
}

extern "C" void kernel_launch(void* const* d_in, const int* in_sizes, int n_in,
                              void* d_out, int out_size, void* d_ws, size_t ws_size,
                              hipStream_t stream)
{
    const float* feats0 = (const float*)d_in[0];
    const int*   coors  = (const int*)d_in[1];
    const float* w[14];
    for (int i = 0; i < 14; ++i) w[i] = (const float*)d_in[3 + i];
    float* out = (float*)d_out;
    const int N = in_sizes[0] / 3;

    // ---- workspace carve-up ----
    char* p = (char*)d_ws;
    int* grid   = (int*)p; p += (size_t)128 * 128 * 128 * 4;  // 8 MB
    int* occ    = (int*)p; p += (size_t)64 * 64 * 64 * 4;     // 1 MB
    int* counts = (int*)p; p += 256;
    int* bsum   = (int*)p; p += 256;
    int* boff   = (int*)p; p += 256;
    int* pairs_t = (int*)p; p += (size_t)N * 32 * 4;          // [row][32]
    int* coordsA = (int*)p; p += (size_t)N * 16;
    int* coordsB = (int*)p; p += (size_t)N * 16;
    unsigned short* featA = (unsigned short*)p; p += (size_t)N * 96 * 2;
    unsigned short* featB = (unsigned short*)p; p += (size_t)N * 96 * 2;
    float* scratch = (float*)p; p += (size_t)4096 * 160 * 4 + 1024;  // deep fp32 acc
    unsigned short* wpBase = (unsigned short*)p;

    static const int CH[14][2] = {{3,64},{64,64},{64,96},{96,96},{96,128},{128,128},
                                  {128,160},{160,160},{160,192},{192,192},{192,224},
                                  {224,224},{224,256},{256,256}};
    unsigned short* wp[14];
    PackArgs pa;
    {
        size_t off = 0;
        int ts = 0;
        for (int i = 1; i < 14; ++i) {
            wp[i] = wpBase + off;
            off += (size_t)27 * CH[i][0] * CH[i][1];
            pa.src[i - 1] = w[i];
            pa.dst[i - 1] = wp[i];
            pa.cin[i - 1] = CH[i][0];
            pa.cout[i - 1] = CH[i][1];
            pa.tileStart[i - 1] = ts;
            ts += 27 * (CH[i][0] / 32) * (CH[i][1] / 16);
        }
        pa.tileStart[13] = ts;
    }

    int bounds[7];
    for (int l = 0; l < 7; ++l) {
        int S = 128 >> l, c = S * S * S;
        bounds[l] = N < c ? N : c;
    }

    set_count_k<<<1, 1, 0, stream>>>(counts, N);
    hipMemsetAsync(d_out, 0, (size_t)out_size * 4, stream);
    pack_all_k<<<cdiv_h(pa.tileStart[13], 4), 256, 0, stream>>>(pa);

    auto build_level = [&](const int* coordsL, int lvl) {
        int S = 128 >> lvl;
        hipMemsetAsync(grid, 0xFF, (size_t)S * S * S * 4, stream);
        int blocks = cdiv_h(bounds[lvl], 256);
        scatter_grid_k<<<blocks, 256, 0, stream>>>(coordsL, counts + lvl, grid, S);
        build_pairs_k<<<blocks, 256, 0, stream>>>(coordsL, counts + lvl, grid, pairs_t, S);
    };

    auto do_pool = [&](const int* coordsL, int lvl, const unsigned short* fin,
                       unsigned short* fout, int C, int* coordsOut) {
        int S = 128 >> lvl, Sh = S / 2, P = Sh * Sh * Sh;
        hipMemsetAsync(occ, 0, (size_t)P * 4, stream);
        mark_occ_k<<<cdiv_h(bounds[lvl], 256), 256, 0, stream>>>(coordsL, counts + lvl, occ, Sh);
        int nb = cdiv_h(P, 4096);
        scan_sum_k<<<nb, 256, 0, stream>>>(occ, P, bsum);
        scan_offsets_k<<<1, 64, 0, stream>>>(bsum, nb, boff, counts + lvl + 1);
        scan_emit_k<<<nb, 256, 0, stream>>>(occ, P, boff, coordsOut, Sh);
        int total = bounds[lvl + 1] * C;
        pool_max_k<<<cdiv_h(total, 256), 256, 0, stream>>>(fin, grid, coordsOut,
                                                           counts + lvl + 1, fout, C, S);
    };

    auto deep_conv = [&](auto launcher, const unsigned short* fin, int wi, int lvl,
                         unsigned short* dst, int COUT) {
        hipMemsetAsync(scratch, 0, (size_t)bounds[lvl] * COUT * 4, stream);
        launcher(fin, wp[wi], pairs_t, counts + lvl, scratch, bounds[lvl], stream);
        f32_to_bf16_k<<<cdiv_h(bounds[lvl] * COUT, 256), 256, 0, stream>>>(
            scratch, counts + lvl, dst, COUT);
    };

    // ---- level 0 ----
    build_level(coors, 0);
    conv0_k<<<cdiv_h(bounds[0], 16), 256, 0, stream>>>(feats0, w[0], pairs_t, counts + 0, featA);
    launch_cm<64, 64, 4, 4, false>(featA, wp[1], pairs_t, counts + 0, featB, bounds[0], stream);
    do_pool(coors, 0, featB, featA, 64, coordsA);
    // ---- level 1 ----
    build_level(coordsA, 1);
    launch_cm<64, 96, 4, 3, false>(featA, wp[2], pairs_t, counts + 1, featB, bounds[1], stream);
    launch_cm<96, 96, 4, 3, false>(featB, wp[3], pairs_t, counts + 1, featA, bounds[1], stream);
    do_pool(coordsA, 1, featA, featB, 96, coordsB);
    // ---- level 2 ----
    build_level(coordsB, 2);
    launch_cm<96, 128, 4, 4, false>(featB, wp[4], pairs_t, counts + 2, featA, bounds[2], stream);
    launch_cm<128, 128, 4, 4, false>(featA, wp[5], pairs_t, counts + 2, featB, bounds[2], stream);
    do_pool(coordsB, 2, featB, featA, 128, coordsA);
    // ---- level 3 (deep) ----
    build_level(coordsA, 3);
    deep_conv(launch_deep<128, 160, 2, 3>, featA, 6, 3, featB, 160);
    deep_conv(launch_deep<160, 160, 2, 3>, featB, 7, 3, featA, 160);
    do_pool(coordsA, 3, featA, featB, 160, coordsB);
    // ---- level 4 (deep) ----
    build_level(coordsB, 4);
    deep_conv(launch_deep<160, 192, 2, 3>, featB, 8, 4, featA, 192);
    deep_conv(launch_deep<192, 192, 2, 3>, featA, 9, 4, featB, 192);
    do_pool(coordsB, 4, featB, featA, 192, coordsA);
    // ---- level 5 (deep) ----
    build_level(coordsA, 5);
    deep_conv(launch_deep<192, 224, 1, 1>, featA, 10, 5, featB, 224);
    deep_conv(launch_deep<224, 224, 1, 1>, featB, 11, 5, featA, 224);
    do_pool(coordsA, 5, featA, featB, 224, coordsB);
    // ---- level 6 (deep) ----
    build_level(coordsB, 6);
    deep_conv(launch_deep<224, 256, 1, 1>, featB, 12, 6, featA, 256);
    // final layer: atomicAdd fp32 straight into d_out (zeroed above)
    launch_deep<256, 256, 1, 1>(featA, wp[13], pairs_t, counts + 6, out, bounds[6], stream);
}

// Round 9
// 745.020 us; speedup vs baseline: 1.1976x; 1.1976x over previous
//
#include <hip/hip_runtime.h>
#include <cstdint>
#include <cstddef>

// ---------------------------------------------------------------------------
// Submanifold sparse conv net, MFMA bf16 implicit-GEMM.
// Round 9: LDS-staged weights (global_load_lds, double-buffered, 1 barrier/tap,
// m97 schedule) for levels 0-2. B feeds MFMA from LDS (throughput ds_read_b128,
// no VGPR pipeline needed); only A-gathers remain latency-critical (2xNS/tap,
// nb prefetched one tap ahead). RT=2 rows/wave, full COUT per wave, no gy split.
// Deep levels (3-6) keep the 1-wave atomic kernel. Structure kernels unchanged.
// ---------------------------------------------------------------------------

typedef __attribute__((ext_vector_type(8))) short short8v;
typedef __attribute__((ext_vector_type(4))) float f32x4;

static inline int cdiv_h(int a, int b) { return (a + b - 1) / b; }

__device__ inline unsigned short f2bf(float f) {
    unsigned int u = __builtin_bit_cast(unsigned int, f);
    u += 0x7FFFu + ((u >> 16) & 1u);
    return (unsigned short)(u >> 16);
}
__device__ inline float bf2f(unsigned short h) {
    unsigned int u = ((unsigned int)h) << 16;
    return __builtin_bit_cast(float, u);
}

// global -> LDS async copy, 16B per lane. LDS dest is wave-uniform base +
// lane*16 (HW behavior); global src is per-lane. Casts via uintptr_t: LDS
// apertures are 4GB-aligned so low 32 bits of a generic LDS pointer are the
// LDS offset (CK idiom).
__device__ inline void gload_lds16(const void* g, void* l) {
    auto gp = (const __attribute__((address_space(1))) unsigned int*)(uintptr_t)g;
    auto lp = (__attribute__((address_space(3))) unsigned int*)(uintptr_t)l;
    __builtin_amdgcn_global_load_lds(gp, lp, 16, 0, 0);
}

__global__ void set_count_k(int* counts, int n) { counts[0] = n; }

__global__ void scatter_grid_k(const int* __restrict__ coords, const int* __restrict__ cnt,
                               int* __restrict__ grid, int S)
{
    int i = blockIdx.x * blockDim.x + threadIdx.x;
    if (i >= cnt[0]) return;
    int z = coords[i * 4 + 1], y = coords[i * 4 + 2], x = coords[i * 4 + 3];
    grid[(z * S + y) * S + x] = i;
}

// pairs_t[row][32]: taps 0..26, pad 27..31 = -1. int4-aligned per row.
__global__ void build_pairs_k(const int* __restrict__ coords, const int* __restrict__ cnt,
                              const int* __restrict__ grid, int* __restrict__ pairs_t, int S)
{
    int i = blockIdx.x * blockDim.x + threadIdx.x;
    if (i >= cnt[0]) return;
    int z = coords[i * 4 + 1], y = coords[i * 4 + 2], x = coords[i * 4 + 3];
    int4* dst = reinterpret_cast<int4*>(pairs_t + (size_t)i * 32);
#pragma unroll
    for (int g = 0; g < 7; ++g) {
        int4 q;
#pragma unroll
        for (int j = 0; j < 4; ++j) {
            int k = g * 4 + j;
            int v = -1;
            if (k < 27) {
                int nz = z + k / 9 - 1;
                int ny = y + (k / 3) % 3 - 1;
                int nx = x + k % 3 - 1;
                if (nz >= 0 && nz < S && ny >= 0 && ny < S && nx >= 0 && nx < S)
                    v = grid[(nz * S + ny) * S + nx];
            }
            ((int*)&q)[j] = v;
        }
        dst[g] = q;
    }
}

// ---- fused weight pre-pack: fp32 [27][CIN][COUT] -> bf16 fragment tiles -----
struct PackArgs {
    const float* src[13];
    unsigned short* dst[13];
    int cin[13];
    int cout[13];
    int tileStart[14];
};

__global__ __launch_bounds__(256) void pack_all_k(PackArgs pa)
{
    int g = blockIdx.x * 4 + ((int)threadIdx.x >> 6);
    int lane = (int)threadIdx.x & 63;
    if (g >= pa.tileStart[13]) return;
    int li = 0;
    while (li < 12 && g >= pa.tileStart[li + 1]) ++li;
    int tile = g - pa.tileStart[li];
    int CIN = pa.cin[li], COUT = pa.cout[li];
    int NS = CIN >> 5, NT = COUT >> 4;
    int t = tile % NT;
    int s = (tile / NT) % NS;
    int k = tile / (NT * NS);
    int kabs = s * 32 + (lane >> 4) * 8;
    int c = t * 16 + (lane & 15);
    const float* src = pa.src[li] + ((size_t)(k * CIN + kabs)) * COUT + c;
    unsigned short* dst = pa.dst[li] + (size_t)tile * 512 + lane * 8;
#pragma unroll
    for (int j = 0; j < 8; ++j) dst[j] = f2bf(src[(size_t)j * COUT]);
}

// ---- first layer (CIN=3) fp32 vector, writes bf16 ---------------------------
__global__ __launch_bounds__(256) void conv0_k(
    const float* __restrict__ fin, const float* __restrict__ W,
    const int* __restrict__ pairs_t, const int* __restrict__ cnt,
    unsigned short* __restrict__ fout)
{
    const int row = blockIdx.x * 16 + ((int)threadIdx.x >> 4);
    const int cg = ((int)threadIdx.x & 15) * 4;
    if (row >= cnt[0]) return;
    float a0 = 0, a1 = 0, a2 = 0, a3 = 0;
    for (int k = 0; k < 27; ++k) {
        int nb = pairs_t[(size_t)row * 32 + k];
        if (nb < 0) continue;
        const float* fr = fin + (size_t)nb * 3;
        const float* wk = W + (size_t)k * 3 * 64 + cg;
#pragma unroll
        for (int ci = 0; ci < 3; ++ci) {
            float f = fr[ci];
            float4 w = *reinterpret_cast<const float4*>(wk + ci * 64);
            a0 += f * w.x; a1 += f * w.y; a2 += f * w.z; a3 += f * w.w;
        }
    }
    size_t o = (size_t)row * 64 + cg;
    fout[o] = f2bf(a0); fout[o + 1] = f2bf(a1);
    fout[o + 2] = f2bf(a2); fout[o + 3] = f2bf(a3);
}

// ---- MFMA conv with LDS-staged B (levels 0-2) --------------------------------
// Block = 4 waves, each wave owns RT row-tiles x full NT cout-tiles.
// Per tap: {barrier; stage(k+1)->buf^1; prefetch nb(k+1); compute(k) from buf}.
// Compiler drains stage's vmcnt at the next barrier (m97 schedule).
template <int CIN, int COUT, int RT, bool OUTF32>
__global__ __launch_bounds__(256) void conv_lds_k(
    const unsigned short* __restrict__ fin, const unsigned short* __restrict__ Wp,
    const int* __restrict__ pairs_t, const int* __restrict__ cnt,
    void* __restrict__ fout)
{
    constexpr int NS = CIN / 32, NT = COUT / 16;
    constexpr int NCH = NS * NT;                 // 1KB chunks per tap
    __shared__ unsigned short sB[2][NCH * 512];  // double-buffered tap tile

    const int lane = (int)threadIdx.x & 63;
    const int wave = (int)threadIdx.x >> 6;
    const int l15 = lane & 15, lhi = lane >> 4;
    const int M = cnt[0];
    const int rowBase = (blockIdx.x * 4 + wave) * (RT * 16);

    const unsigned short* __restrict__ finL = fin + (size_t)lhi * 8;

    f32x4 acc[RT][NT];
#pragma unroll
    for (int a = 0; a < RT; ++a)
#pragma unroll
        for (int b = 0; b < NT; ++b) acc[a][b] = (f32x4){0.f, 0.f, 0.f, 0.f};

    int  rowC[RT];
    bool rOK[RT];
#pragma unroll
    for (int rt = 0; rt < RT; ++rt) {
        int r = rowBase + rt * 16 + l15;
        rOK[rt]  = r < M;
        rowC[rt] = rOK[rt] ? r : 0;
    }

    // stage(K) into buffer BUF: whole block copies NCH KB, wave-strided chunks
#define STAGE(K, BUF)                                                            \
    {                                                                            \
        const unsigned short* src =                                              \
            Wp + (size_t)(K) * (NCH * 512) + (size_t)lane * 8;                   \
        _Pragma("unroll") for (int idx = wave; idx < NCH; idx += 4)              \
            gload_lds16(src + (size_t)idx * 512, &sB[BUF][idx * 512]);           \
    }

    int nbCur[RT], nbNxt[RT];
#pragma unroll
    for (int rt = 0; rt < RT; ++rt)
        nbCur[rt] = rOK[rt] ? pairs_t[(size_t)rowC[rt] * 32 + 0] : -1;

    STAGE(0, 0);

    for (int k = 0; k < 27; ++k) {
        __syncthreads();  // buf[k&1] staged & visible; buf[(k+1)&1] free
        if (k < 26) {
            STAGE(k + 1, (k + 1) & 1);
#pragma unroll
            for (int rt = 0; rt < RT; ++rt)
                nbNxt[rt] = rOK[rt] ? pairs_t[(size_t)rowC[rt] * 32 + (k + 1)] : -1;
        }

        int nb[RT], act[RT];
        bool anyAct = false;
#pragma unroll
        for (int rt = 0; rt < RT; ++rt) {
            nb[rt] = nbCur[rt];
            act[rt] = __any(nb[rt] >= 0);
            anyAct = anyAct || (act[rt] != 0);
        }
#pragma unroll
        for (int rt = 0; rt < RT; ++rt) nbCur[rt] = nbNxt[rt];

        if (anyAct) {
            const unsigned short* __restrict__ buf = sB[k & 1];
            short8v afr[NS][RT];
#pragma unroll
            for (int s = 0; s < NS; ++s)
#pragma unroll
                for (int rt = 0; rt < RT; ++rt) {
                    afr[s][rt] = (short8v){};
                    if (nb[rt] >= 0)
                        afr[s][rt] = *reinterpret_cast<const short8v*>(
                            finL + (size_t)nb[rt] * CIN + s * 32);
                }
#pragma unroll
            for (int s = 0; s < NS; ++s)
#pragma unroll
                for (int rt = 0; rt < RT; ++rt) {
                    if (!act[rt]) continue;
#pragma unroll
                    for (int t = 0; t < NT; ++t) {
                        short8v b = *reinterpret_cast<const short8v*>(
                            &buf[(s * NT + t) * 512 + lane * 8]);
                        acc[rt][t] = __builtin_amdgcn_mfma_f32_16x16x32_bf16(
                            afr[s][rt], b, acc[rt][t], 0, 0, 0);
                    }
                }
        }
    }
#undef STAGE

    // epilogue: C layout col = lane&15, row = (lane>>4)*4 + reg
#pragma unroll
    for (int rt = 0; rt < RT; ++rt) {
#pragma unroll
        for (int j = 0; j < 4; ++j) {
            int r = rowBase + rt * 16 + lhi * 4 + j;
            if (r >= M) continue;
#pragma unroll
            for (int t = 0; t < NT; ++t) {
                int c = t * 16 + l15;
                if constexpr (OUTF32)
                    ((float*)fout)[(size_t)r * COUT + c] = acc[rt][t][j];
                else
                    ((unsigned short*)fout)[(size_t)r * COUT + c] = f2bf(acc[rt][t][j]);
            }
        }
    }
}

// ---- deep-level conv (levels 3-6): 1-wave blocks, tap/cout split, fp32 atomics
template <int CIN, int COUT, int CTD, int TG>
__global__ __launch_bounds__(64) void conv_deep_k(
    const unsigned short* __restrict__ fin, const unsigned short* __restrict__ Wp,
    const int* __restrict__ pairs_t, const int* __restrict__ cnt,
    float* __restrict__ fout)
{
    constexpr int NS = CIN / 32, NT = COUT / 16;
    const int lane = (int)threadIdx.x;
    const int l15 = lane & 15, lhi = lane >> 4;
    const int M = cnt[0];
    if ((int)blockIdx.x * 16 >= M) return;
    const int row = blockIdx.x * 16 + l15;
    const int ct0 = blockIdx.y * CTD;
    const int k0 = blockIdx.z * TG;

    f32x4 acc[CTD];
#pragma unroll
    for (int t = 0; t < CTD; ++t) acc[t] = (f32x4){0.f, 0.f, 0.f, 0.f};

    bool anyTap = false;
#pragma unroll
    for (int kk = 0; kk < TG; ++kk) {
        const int k = k0 + kk;
        int nb = (row < M) ? pairs_t[(size_t)row * 32 + k] : -1;
        if (!__any(nb >= 0)) continue;
        anyTap = true;
        const unsigned short* wk = Wp + (size_t)k * NS * NT * 512 + (size_t)lane * 8;
#pragma unroll
        for (int s = 0; s < NS; ++s) {
            short8v a = (short8v){};
            if (nb >= 0)
                a = *reinterpret_cast<const short8v*>(
                    fin + (size_t)nb * CIN + s * 32 + lhi * 8);
#pragma unroll
            for (int t = 0; t < CTD; ++t) {
                short8v b = *reinterpret_cast<const short8v*>(
                    wk + ((size_t)s * NT + ct0 + t) * 512);
                acc[t] = __builtin_amdgcn_mfma_f32_16x16x32_bf16(a, b, acc[t], 0, 0, 0);
            }
        }
    }
    if (!anyTap) return;

#pragma unroll
    for (int t = 0; t < CTD; ++t)
#pragma unroll
        for (int j = 0; j < 4; ++j) {
            int r = blockIdx.x * 16 + lhi * 4 + j;
            if (r < M)
                atomicAdd(&fout[(size_t)r * COUT + (ct0 + t) * 16 + l15], acc[t][j]);
        }
}

__global__ __launch_bounds__(256) void f32_to_bf16_k(
    const float* __restrict__ src, const int* __restrict__ cnt,
    unsigned short* __restrict__ dst, int C)
{
    int idx = blockIdx.x * 256 + (int)threadIdx.x;
    if (idx / C >= cnt[0]) return;
    dst[idx] = f2bf(src[idx]);
}

// ---- pooling structure: multi-block scan ------------------------------------
__global__ void mark_occ_k(const int* __restrict__ coords, const int* __restrict__ cnt,
                           int* __restrict__ occ, int Sh)
{
    int i = blockIdx.x * blockDim.x + threadIdx.x;
    if (i >= cnt[0]) return;
    int z = coords[i * 4 + 1] >> 1, y = coords[i * 4 + 2] >> 1, x = coords[i * 4 + 3] >> 1;
    occ[(z * Sh + y) * Sh + x] = 1;
}

__global__ __launch_bounds__(256) void scan_sum_k(const int* __restrict__ occ, int P,
                                                  int* __restrict__ bsum)
{
    int base = blockIdx.x * 4096 + (int)threadIdx.x * 16;
    int s = 0;
#pragma unroll
    for (int j = 0; j < 16; ++j) { int i = base + j; s += (i < P) ? occ[i] : 0; }
    for (int off = 1; off < 64; off <<= 1) s += __shfl_xor(s, off);
    __shared__ int ws[4];
    if ((threadIdx.x & 63) == 0) ws[threadIdx.x >> 6] = s;
    __syncthreads();
    if (threadIdx.x == 0) bsum[blockIdx.x] = ws[0] + ws[1] + ws[2] + ws[3];
}

__global__ void scan_offsets_k(const int* __restrict__ bsum, int nb,
                               int* __restrict__ boff, int* __restrict__ cntOut)
{
    int lane = threadIdx.x;  // 64 threads, nb <= 64
    int v = (lane < nb) ? bsum[lane] : 0;
    int incl = v;
    for (int off = 1; off < 64; off <<= 1) {
        int t = __shfl_up(incl, off);
        if (lane >= off) incl += t;
    }
    if (lane < nb) boff[lane] = incl - v;
    if (lane == 63) cntOut[0] = incl;
}

__global__ __launch_bounds__(256) void scan_emit_k(const int* __restrict__ occ, int P,
                                                   const int* __restrict__ boff,
                                                   int* __restrict__ newcoords, int Sh)
{
    __shared__ int ws[4];
    int tid = threadIdx.x;
    int base = blockIdx.x * 4096 + tid * 16;
    int v[16];
    int s = 0;
#pragma unroll
    for (int j = 0; j < 16; ++j) { int i = base + j; v[j] = (i < P) ? occ[i] : 0; s += v[j]; }
    int mysum = s;
    int incl = s;
    for (int off = 1; off < 64; off <<= 1) {
        int t = __shfl_up(incl, off);
        if ((tid & 63) >= off) incl += t;
    }
    if ((tid & 63) == 63) ws[tid >> 6] = incl;
    __syncthreads();
    int waveOff = 0;
    for (int w = 0; w < (tid >> 6); ++w) waveOff += ws[w];
    int r = boff[blockIdx.x] + waveOff + incl - mysum;
    const int SS = Sh * Sh;
#pragma unroll
    for (int j = 0; j < 16; ++j) {
        if (v[j]) {
            int c = base + j;
            newcoords[r * 4 + 0] = 0;
            newcoords[r * 4 + 1] = c / SS;
            newcoords[r * 4 + 2] = (c % SS) / Sh;
            newcoords[r * 4 + 3] = c % Sh;
            ++r;
        }
    }
}

__global__ void pool_max_k(const unsigned short* __restrict__ fin, const int* __restrict__ gridPrev,
                           const int* __restrict__ newcoords, const int* __restrict__ cnt,
                           unsigned short* __restrict__ fout, int C, int Sprev)
{
    int idx = blockIdx.x * blockDim.x + threadIdx.x;
    int r = idx / C, c = idx % C;
    if (r >= cnt[0]) return;
    int z2 = newcoords[r * 4 + 1] * 2;
    int y2 = newcoords[r * 4 + 2] * 2;
    int x2 = newcoords[r * 4 + 3] * 2;
    float best = -3.4e38f;
    unsigned short bb = 0;
#pragma unroll
    for (int d = 0; d < 8; ++d) {
        int z = z2 + (d >> 2), y = y2 + ((d >> 1) & 1), x = x2 + (d & 1);
        int j = gridPrev[(z * Sprev + y) * Sprev + x];
        if (j >= 0) {
            unsigned short u = fin[(size_t)j * C + c];
            float f = bf2f(u);
            if (f > best) { best = f; bb = u; }
        }
    }
    fout[(size_t)r * C + c] = bb;
}

// ---------------------------------------------------------------------------

template <int CIN, int COUT, int RT, bool OUTF32>
static void launch_cl(const unsigned short* fin, const unsigned short* Wp,
                      const int* pairs_t, const int* cnt, void* fout,
                      int bound, hipStream_t stream)
{
    static_assert(CIN % 32 == 0 && COUT % 16 == 0, "shape");
    dim3 g(cdiv_h(bound, RT * 64));
    conv_lds_k<CIN, COUT, RT, OUTF32><<<g, 256, 0, stream>>>(fin, Wp, pairs_t, cnt, fout);
}

template <int CIN, int COUT, int CTD, int TG>
static void launch_deep(const unsigned short* fin, const unsigned short* Wp,
                        const int* pairs_t, const int* cnt, float* acc,
                        int bound, hipStream_t stream)
{
    constexpr int NT = COUT / 16;
    static_assert(NT % CTD == 0 && 27 % TG == 0, "shape");
    dim3 g(cdiv_h(bound, 16), NT / CTD, 27 / TG);
    conv_deep_k<CIN, COUT, CTD, TG><<<g, 64, 0, stream>>>(fin, Wp, pairs_t, cnt, acc);
}

extern "C" void kernel_launch(void* const* d_in, const int* in_sizes, int n_in,
                              void* d_out, int out_size, void* d_ws, size_t ws_size,
                              hipStream_t stream)
{
    const float* feats0 = (const float*)d_in[0];
    const int*   coors  = (const int*)d_in[1];
    const float* w[14];
    for (int i = 0; i < 14; ++i) w[i] = (const float*)d_in[3 + i];
    float* out = (float*)d_out;
    const int N = in_sizes[0] / 3;

    // ---- workspace carve-up ----
    char* p = (char*)d_ws;
    int* grid   = (int*)p; p += (size_t)128 * 128 * 128 * 4;  // 8 MB
    int* occ    = (int*)p; p += (size_t)64 * 64 * 64 * 4;     // 1 MB
    int* counts = (int*)p; p += 256;
    int* bsum   = (int*)p; p += 256;
    int* boff   = (int*)p; p += 256;
    int* pairs_t = (int*)p; p += (size_t)N * 32 * 4;          // [row][32]
    int* coordsA = (int*)p; p += (size_t)N * 16;
    int* coordsB = (int*)p; p += (size_t)N * 16;
    unsigned short* featA = (unsigned short*)p; p += (size_t)N * 96 * 2;
    unsigned short* featB = (unsigned short*)p; p += (size_t)N * 96 * 2;
    float* scratch = (float*)p; p += (size_t)4096 * 160 * 4 + 1024;  // deep fp32 acc
    unsigned short* wpBase = (unsigned short*)p;

    static const int CH[14][2] = {{3,64},{64,64},{64,96},{96,96},{96,128},{128,128},
                                  {128,160},{160,160},{160,192},{192,192},{192,224},
                                  {224,224},{224,256},{256,256}};
    unsigned short* wp[14];
    PackArgs pa;
    {
        size_t off = 0;
        int ts = 0;
        for (int i = 1; i < 14; ++i) {
            wp[i] = wpBase + off;
            off += (size_t)27 * CH[i][0] * CH[i][1];
            pa.src[i - 1] = w[i];
            pa.dst[i - 1] = wp[i];
            pa.cin[i - 1] = CH[i][0];
            pa.cout[i - 1] = CH[i][1];
            pa.tileStart[i - 1] = ts;
            ts += 27 * (CH[i][0] / 32) * (CH[i][1] / 16);
        }
        pa.tileStart[13] = ts;
    }

    int bounds[7];
    for (int l = 0; l < 7; ++l) {
        int S = 128 >> l, c = S * S * S;
        bounds[l] = N < c ? N : c;
    }

    set_count_k<<<1, 1, 0, stream>>>(counts, N);
    hipMemsetAsync(d_out, 0, (size_t)out_size * 4, stream);
    pack_all_k<<<cdiv_h(pa.tileStart[13], 4), 256, 0, stream>>>(pa);

    auto build_level = [&](const int* coordsL, int lvl) {
        int S = 128 >> lvl;
        hipMemsetAsync(grid, 0xFF, (size_t)S * S * S * 4, stream);
        int blocks = cdiv_h(bounds[lvl], 256);
        scatter_grid_k<<<blocks, 256, 0, stream>>>(coordsL, counts + lvl, grid, S);
        build_pairs_k<<<blocks, 256, 0, stream>>>(coordsL, counts + lvl, grid, pairs_t, S);
    };

    auto do_pool = [&](const int* coordsL, int lvl, const unsigned short* fin,
                       unsigned short* fout, int C, int* coordsOut) {
        int S = 128 >> lvl, Sh = S / 2, P = Sh * Sh * Sh;
        hipMemsetAsync(occ, 0, (size_t)P * 4, stream);
        mark_occ_k<<<cdiv_h(bounds[lvl], 256), 256, 0, stream>>>(coordsL, counts + lvl, occ, Sh);
        int nb = cdiv_h(P, 4096);
        scan_sum_k<<<nb, 256, 0, stream>>>(occ, P, bsum);
        scan_offsets_k<<<1, 64, 0, stream>>>(bsum, nb, boff, counts + lvl + 1);
        scan_emit_k<<<nb, 256, 0, stream>>>(occ, P, boff, coordsOut, Sh);
        int total = bounds[lvl + 1] * C;
        pool_max_k<<<cdiv_h(total, 256), 256, 0, stream>>>(fin, grid, coordsOut,
                                                           counts + lvl + 1, fout, C, S);
    };

    auto deep_conv = [&](auto launcher, const unsigned short* fin, int wi, int lvl,
                         unsigned short* dst, int COUT) {
        hipMemsetAsync(scratch, 0, (size_t)bounds[lvl] * COUT * 4, stream);
        launcher(fin, wp[wi], pairs_t, counts + lvl, scratch, bounds[lvl], stream);
        f32_to_bf16_k<<<cdiv_h(bounds[lvl] * COUT, 256), 256, 0, stream>>>(
            scratch, counts + lvl, dst, COUT);
    };

    // ---- level 0 ----
    build_level(coors, 0);
    conv0_k<<<cdiv_h(bounds[0], 16), 256, 0, stream>>>(feats0, w[0], pairs_t, counts + 0, featA);
    launch_cl<64, 64, 2, false>(featA, wp[1], pairs_t, counts + 0, featB, bounds[0], stream);
    do_pool(coors, 0, featB, featA, 64, coordsA);
    // ---- level 1 ----
    build_level(coordsA, 1);
    launch_cl<64, 96, 2, false>(featA, wp[2], pairs_t, counts + 1, featB, bounds[1], stream);
    launch_cl<96, 96, 2, false>(featB, wp[3], pairs_t, counts + 1, featA, bounds[1], stream);
    do_pool(coordsA, 1, featA, featB, 96, coordsB);
    // ---- level 2 ----
    build_level(coordsB, 2);
    launch_cl<96, 128, 2, false>(featB, wp[4], pairs_t, counts + 2, featA, bounds[2], stream);
    launch_cl<128, 128, 2, false>(featA, wp[5], pairs_t, counts + 2, featB, bounds[2], stream);
    do_pool(coordsB, 2, featB, featA, 128, coordsA);
    // ---- level 3 (deep) ----
    build_level(coordsA, 3);
    deep_conv(launch_deep<128, 160, 2, 3>, featA, 6, 3, featB, 160);
    deep_conv(launch_deep<160, 160, 2, 3>, featB, 7, 3, featA, 160);
    do_pool(coordsA, 3, featA, featB, 160, coordsB);
    // ---- level 4 (deep) ----
    build_level(coordsB, 4);
    deep_conv(launch_deep<160, 192, 2, 3>, featB, 8, 4, featA, 192);
    deep_conv(launch_deep<192, 192, 2, 3>, featA, 9, 4, featB, 192);
    do_pool(coordsB, 4, featB, featA, 192, coordsA);
    // ---- level 5 (deep) ----
    build_level(coordsA, 5);
    deep_conv(launch_deep<192, 224, 1, 1>, featA, 10, 5, featB, 224);
    deep_conv(launch_deep<224, 224, 1, 1>, featB, 11, 5, featA, 224);
    do_pool(coordsA, 5, featA, featB, 224, coordsB);
    // ---- level 6 (deep) ----
    build_level(coordsB, 6);
    deep_conv(launch_deep<224, 256, 1, 1>, featB, 12, 6, featA, 256);
    // final layer: atomicAdd fp32 straight into d_out (zeroed above)
    launch_deep<256, 256, 1, 1>(featA, wp[13], pairs_t, counts + 6, out, bounds[6], stream);
}